// Round 1
// baseline (342.815 us; speedup 1.0000x reference)
//
#include <hip/hip_runtime.h>
#include <math.h>

// Problem constants (B,C,H,W = 4,64,64,64)
#define BATCH 4
#define CCH   64      // C
#define CF    8       // C/8 (f,g channels)
#define NPIX  4096    // N = H*W
#define TQ    64      // query tile
#define TK    64      // key tile

// ---------------------------------------------------------------------------
// Kernel 1: fused projections.
// P[b][o][n], o in [0,80): 0..7 = f, 8..15 = g, 16..79 = hv.
// grid: (NPIX/256, 5, BATCH), block 256. Each thread: one pixel n, 16 rows.
// Weight/bias reads are wave-uniform -> scalar loads (s_load), x reads
// coalesced across n.
// ---------------------------------------------------------------------------
__global__ __launch_bounds__(256) void proj_kernel(
    const float* __restrict__ x,
    const float* __restrict__ Wf, const float* __restrict__ bf,
    const float* __restrict__ Wg, const float* __restrict__ bg,
    const float* __restrict__ Wh, const float* __restrict__ bh,
    float* __restrict__ P)
{
    const int n  = blockIdx.x * 256 + threadIdx.x;
    const int o0 = blockIdx.y * 16;          // first of 16 output rows
    const int b  = blockIdx.z;

    // load x[b][:][n] into registers (64 coalesced loads)
    float xv[CCH];
    const float* xp = x + (size_t)b * CCH * NPIX + n;
#pragma unroll
    for (int c = 0; c < CCH; ++c) xv[c] = xp[(size_t)c * NPIX];

    float acc[16];
#pragma unroll
    for (int k = 0; k < 16; ++k) {
        const int o = o0 + k;
        const float* wrow;
        float bias;
        if (o < 8)       { wrow = Wf + o * CCH;        bias = bf[o];      }
        else if (o < 16) { wrow = Wg + (o - 8) * CCH;  bias = bg[o - 8];  }
        else             { wrow = Wh + (o - 16) * CCH; bias = bh[o - 16]; }
        float a = bias;
#pragma unroll
        for (int c = 0; c < CCH; ++c) a += wrow[c] * xv[c];
        acc[k] = a;
    }

    float* pp = P + (size_t)b * 80 * NPIX + (size_t)o0 * NPIX + n;
#pragma unroll
    for (int k = 0; k < 16; ++k) pp[(size_t)k * NPIX] = acc[k];
}

// ---------------------------------------------------------------------------
// Kernel 2: flash-style attention, fp32.
// One block = (batch b, query tile of TQ=64). 256 threads = 4 waves.
// Online softmax across TK=64 key tiles; PV register-blocked 4 rows x 4 ch.
// ---------------------------------------------------------------------------
__global__ __launch_bounds__(256) void attn_kernel(
    const float* __restrict__ P,      // [B][80][N]
    const float* __restrict__ x,      // [B][C][N]
    const float* __restrict__ gamma,  // [1]
    float* __restrict__ out)          // [B][C][N]
{
    const int b  = blockIdx.y;
    const int i0 = blockIdx.x * TQ;
    const int t  = threadIdx.x;

    const float* Pb   = P + (size_t)b * 80 * NPIX;
    const float* fptr = Pb;                 // [8][N]
    const float* gptr = Pb + 8 * NPIX;      // [8][N]
    const float* hptr = Pb + 16 * NPIX;     // [64][N]

    __shared__ float g_lds[TK][CF];         // [j][c]  2 KB
    __shared__ float hv_lds[TK][CCH];       // [j][c] 16 KB
    __shared__ float p_lds[TK][TQ];         // [j][i] 16 KB
    __shared__ float red_max[4][TQ];
    __shared__ float red_sum[4][TQ];
    __shared__ float alpha_lds[TQ];
    __shared__ float l_lds[TQ];

    // score/softmax-phase mapping: row is = t&63, j-quarter q = t>>6
    const int is = t & 63;
    const int q  = t >> 6;
    // PV-phase mapping: rows rib*4..+3, channels cib*4..+3
    const int rib = t & 15;
    const int cib = t >> 4;

    // f[:, i0+is] in registers (replicated across the 4 waves)
    float fr[CF];
#pragma unroll
    for (int c = 0; c < CF; ++c) fr[c] = fptr[(size_t)c * NPIX + i0 + is];

    float m_i = -INFINITY, l_i = 0.f;
    float o_acc[4][4];
#pragma unroll
    for (int r = 0; r < 4; ++r)
#pragma unroll
        for (int cc = 0; cc < 4; ++cc) o_acc[r][cc] = 0.f;

    for (int kt = 0; kt < NPIX / TK; ++kt) {
        const int j0 = kt * TK;

        // ---- stage g tile: g_lds[j][c] (2 elements/thread, coalesced in j)
        g_lds[is][q]     = gptr[(size_t)q       * NPIX + j0 + is];
        g_lds[is][q + 4] = gptr[(size_t)(q + 4) * NPIX + j0 + is];

        // ---- stage hv tile: thread owns channel cs=is, 16 consecutive j
        {
            const int jb = q * 16;
            const float* hsrc = hptr + (size_t)is * NPIX + j0 + jb;
#pragma unroll
            for (int u = 0; u < 4; ++u) {
                float4 hvv = *(const float4*)(hsrc + 4 * u);
                hv_lds[jb + 4*u + 0][is] = hvv.x;
                hv_lds[jb + 4*u + 1][is] = hvv.y;
                hv_lds[jb + 4*u + 2][is] = hvv.z;
                hv_lds[jb + 4*u + 3][is] = hvv.w;
            }
        }
        __syncthreads();

        // ---- scores: s[is][j] for 16 j's (g_lds reads are wave-broadcast)
        float sreg[16];
        float lmax = -INFINITY;
#pragma unroll
        for (int jj = 0; jj < 16; ++jj) {
            const int j = q * 16 + jj;
            const float4 g0 = *(const float4*)&g_lds[j][0];
            const float4 g1 = *(const float4*)&g_lds[j][4];
            float s = fr[0]*g0.x + fr[1]*g0.y + fr[2]*g0.z + fr[3]*g0.w
                    + fr[4]*g1.x + fr[5]*g1.y + fr[6]*g1.z + fr[7]*g1.w;
            sreg[jj] = s;
            lmax = fmaxf(lmax, s);
        }
        red_max[q][is] = lmax;
        __syncthreads();

        // ---- online softmax update (replicated per row across 4 threads)
        const float tmax = fmaxf(fmaxf(red_max[0][is], red_max[1][is]),
                                 fmaxf(red_max[2][is], red_max[3][is]));
        const float new_m = fmaxf(m_i, tmax);
        const float alpha = __expf(m_i - new_m);   // 0 on first tile
        float lsum = 0.f;
#pragma unroll
        for (int jj = 0; jj < 16; ++jj) {
            const float p = __expf(sreg[jj] - new_m);
            p_lds[q * 16 + jj][is] = p;
            lsum += p;
        }
        red_sum[q][is] = lsum;
        if (q == 0) alpha_lds[is] = alpha;
        m_i = new_m;
        __syncthreads();

        l_i = alpha * l_i +
              (red_sum[0][is] + red_sum[1][is] + red_sum[2][is] + red_sum[3][is]);

        // ---- PV: o[c][i] += sum_j p[i][j] * hv[c][j], 4x4 register block
        {
            float al[4];
#pragma unroll
            for (int r = 0; r < 4; ++r) al[r] = alpha_lds[rib * 4 + r];
#pragma unroll
            for (int r = 0; r < 4; ++r)
#pragma unroll
                for (int cc = 0; cc < 4; ++cc) o_acc[r][cc] *= al[r];

#pragma unroll 8
            for (int j = 0; j < TK; ++j) {
                const float4 pv = *(const float4*)&p_lds[j][rib * 4];
                const float4 hh = *(const float4*)&hv_lds[j][cib * 4];
                o_acc[0][0] += pv.x * hh.x;  o_acc[0][1] += pv.x * hh.y;
                o_acc[0][2] += pv.x * hh.z;  o_acc[0][3] += pv.x * hh.w;
                o_acc[1][0] += pv.y * hh.x;  o_acc[1][1] += pv.y * hh.y;
                o_acc[1][2] += pv.y * hh.z;  o_acc[1][3] += pv.y * hh.w;
                o_acc[2][0] += pv.z * hh.x;  o_acc[2][1] += pv.z * hh.y;
                o_acc[2][2] += pv.z * hh.z;  o_acc[2][3] += pv.z * hh.w;
                o_acc[3][0] += pv.w * hh.x;  o_acc[3][1] += pv.w * hh.y;
                o_acc[3][2] += pv.w * hh.z;  o_acc[3][3] += pv.w * hh.w;
            }
        }
        __syncthreads();   // protect g_lds/hv_lds/p_lds/red_* for next tile
    }

    // ---- epilogue: out = gamma * o/l + x
    if (q == 0) l_lds[is] = l_i;
    __syncthreads();

    const float gam = gamma[0];
    float rl[4];
#pragma unroll
    for (int r = 0; r < 4; ++r) rl[r] = 1.f / l_lds[rib * 4 + r];

#pragma unroll
    for (int cc = 0; cc < 4; ++cc) {
        const int c = cib * 4 + cc;
        const size_t base = (size_t)b * CCH * NPIX + (size_t)c * NPIX
                          + i0 + rib * 4;
        const float4 xr = *(const float4*)(x + base);
        float4 ov;
        ov.x = gam * (o_acc[0][cc] * rl[0]) + xr.x;
        ov.y = gam * (o_acc[1][cc] * rl[1]) + xr.y;
        ov.z = gam * (o_acc[2][cc] * rl[2]) + xr.z;
        ov.w = gam * (o_acc[3][cc] * rl[3]) + xr.w;
        *(float4*)(out + base) = ov;
    }
}

// ---------------------------------------------------------------------------
extern "C" void kernel_launch(void* const* d_in, const int* in_sizes, int n_in,
                              void* d_out, int out_size, void* d_ws, size_t ws_size,
                              hipStream_t stream)
{
    const float* x     = (const float*)d_in[0];
    const float* Wf    = (const float*)d_in[1];
    const float* bf    = (const float*)d_in[2];
    const float* Wg    = (const float*)d_in[3];
    const float* bg    = (const float*)d_in[4];
    const float* Wh    = (const float*)d_in[5];
    const float* bh    = (const float*)d_in[6];
    const float* gamma = (const float*)d_in[7];
    float* out = (float*)d_out;
    float* P   = (float*)d_ws;   // needs 4*80*4096*4 = 5.25 MB

    dim3 g1(NPIX / 256, 5, BATCH);
    proj_kernel<<<g1, dim3(256), 0, stream>>>(x, Wf, bf, Wg, bg, Wh, bh, P);

    dim3 g2(NPIX / TQ, BATCH);
    attn_kernel<<<g2, dim3(256), 0, stream>>>(P, x, gamma, out);
}

// Round 2
// 164.248 us; speedup vs baseline: 2.0872x; 2.0872x over previous
//
#include <hip/hip_runtime.h>
#include <hip/hip_bf16.h>
#include <math.h>

// Problem constants (B,C,H,W = 4,64,64,64)
#define BATCH 4
#define CCH   64      // C
#define CF    8       // C/8
#define NPIX  4096    // N = H*W
#define TQ    64
#define TK    64
#define NT    (NPIX / TK)

typedef short bf16x8 __attribute__((ext_vector_type(8)));
typedef float f32x4  __attribute__((ext_vector_type(4)));
typedef unsigned short u16;

// async global->LDS, 16 B per lane. LDS dest semantics: wave-uniform base +
// lane*16 (m104/m108); we pass the per-lane matching address.
__device__ __forceinline__ void async_copy16(void* lds, const void* gsrc) {
    __builtin_amdgcn_global_load_lds(
        (const __attribute__((address_space(1))) unsigned int*)gsrc,
        (__attribute__((address_space(3))) unsigned int*)lds, 16, 0, 0);
}

__device__ __forceinline__ u16 f2bf(float v) {
    __hip_bfloat16 h = __float2bfloat16(v);
    return *(u16*)&h;
}

// ---------------------------------------------------------------------------
// Kernel 1: projections -> bf16 workspace.
//   fT[b][n][8], gT[b][n][8]  (transposed: 16B/pixel, global_load_lds-ready)
//   hv[b][c][n]               (c-major)
// grid (NPIX/256, 5, BATCH), block 256. grp 0 = f+g rows, grps 1..4 = hv rows.
// ---------------------------------------------------------------------------
__global__ __launch_bounds__(256) void proj_kernel(
    const float* __restrict__ x,
    const float* __restrict__ Wf, const float* __restrict__ bf,
    const float* __restrict__ Wg, const float* __restrict__ bg,
    const float* __restrict__ Wh, const float* __restrict__ bh,
    u16* __restrict__ fT, u16* __restrict__ gT, u16* __restrict__ hv)
{
    const int n   = blockIdx.x * 256 + threadIdx.x;
    const int grp = blockIdx.y;
    const int b   = blockIdx.z;

    float xv[CCH];
    const float* xp = x + (size_t)b * CCH * NPIX + n;
#pragma unroll
    for (int c = 0; c < CCH; ++c) xv[c] = xp[(size_t)c * NPIX];

    if (grp == 0) {
        union { u16 u[8]; uint4 v; } fpk, gpk;
#pragma unroll
        for (int k = 0; k < 16; ++k) {
            const float* wrow = (k < 8) ? (Wf + k * CCH) : (Wg + (k - 8) * CCH);
            float a = (k < 8) ? bf[k] : bg[k - 8];
#pragma unroll
            for (int c = 0; c < CCH; ++c) a += wrow[c] * xv[c];
            if (k < 8) fpk.u[k] = f2bf(a); else gpk.u[k - 8] = f2bf(a);
        }
        *(uint4*)(fT + ((size_t)b * NPIX + n) * 8) = fpk.v;
        *(uint4*)(gT + ((size_t)b * NPIX + n) * 8) = gpk.v;
    } else {
        const int c0 = (grp - 1) * 16;
#pragma unroll
        for (int k = 0; k < 16; ++k) {
            const float* wrow = Wh + (c0 + k) * CCH;
            float a = bh[c0 + k];
#pragma unroll
            for (int c = 0; c < CCH; ++c) a += wrow[c] * xv[c];
            hv[((size_t)b * CCH + c0 + k) * NPIX + n] = f2bf(a);
        }
    }
}

// ---------------------------------------------------------------------------
// Kernel 2: flash attention on MFMA (16x16x32 bf16).
// Block = (b, 64-query tile), 4 waves; wave w owns query subtile i = w*16+ln.
// QK^T: A=g[j][c] (K=8 padded to 32, quad0 only), B=f[i][c]. D[j][i]:
//   col=i=lane&15, rows j=quad*4+reg -> softmax: in-lane + shfl_xor(16,32).
// PV: A=hv[c][j] (XOR-swizzled LDS), B=P[i][j] (LDS round-trip, stride 72).
// ---------------------------------------------------------------------------
__global__ __launch_bounds__(256) void attn_kernel(
    const u16* __restrict__ fT, const u16* __restrict__ gT,
    const u16* __restrict__ hv, const float* __restrict__ x,
    const float* __restrict__ gamma, float* __restrict__ out)
{
    const int b    = blockIdx.y;
    const int i0   = blockIdx.x * TQ;
    const int tid  = threadIdx.x;
    const int wave = tid >> 6;
    const int lane = tid & 63;
    const int ln   = lane & 15;
    const int quad = lane >> 4;

    __shared__ u16 f_lds[TQ * 8];            // [i][c]           1 KB
    __shared__ u16 g_lds[2][TK * 8];         // [j][c]  dbuf   2x1 KB
    __shared__ u16 hv_lds[2][CCH * TK];      // [c][j^swz] dbuf 2x8 KB
    __shared__ u16 p_lds[TQ * 72];           // [i][j], +8 pad  9 KB

    const u16* fTb = fT + (size_t)b * NPIX * 8;
    const u16* gTb = gT + (size_t)b * NPIX * 8;
    const u16* hvb = hv + (size_t)b * CCH * NPIX;

    // stage hv tile (8 chunks of 1KB: wave w does chunks 2w,2w+1) + g (wave 0)
    auto stage = [&](int kt, int buf) {
        const int j0 = kt * TK;
#pragma unroll
        for (int u = 0; u < 2; ++u) {
            const int chunk = wave * 2 + u;
            const int c  = chunk * 8 + (lane >> 3);
            const int jg = (lane & 7) ^ (lane >> 3);   // XOR swizzle
            async_copy16(&hv_lds[buf][chunk * 512 + lane * 8],
                         hvb + (size_t)c * NPIX + j0 + jg * 8);
        }
        if (wave == 0)
            async_copy16(&g_lds[buf][lane * 8], gTb + (size_t)(j0 + lane) * 8);
    };

    // pre-loop: stage tile 0 + f
    stage(0, 0);
    if (wave == 0)
        async_copy16(&f_lds[lane * 8], fTb + (size_t)(i0 + lane) * 8);

    float  m_i = -INFINITY, l_i = 0.f;
    f32x4  acc[4];
#pragma unroll
    for (int ct = 0; ct < 4; ++ct) acc[ct] = (f32x4){0.f, 0.f, 0.f, 0.f};
    bf16x8 f_frag = {0, 0, 0, 0, 0, 0, 0, 0};

    int buf = 0;
    for (int kt = 0; kt < NT; ++kt) {
        __syncthreads();   // #1: drains own staging vmcnt; all cur buffers resident

        if (kt == 0 && quad == 0)
            f_frag = *(const bf16x8*)&f_lds[(wave * 16 + ln) * 8];

        // ---- QK^T: 4 j-subtiles
        f32x4 s[4];
#pragma unroll
        for (int jt = 0; jt < 4; ++jt) {
            bf16x8 ga = {0, 0, 0, 0, 0, 0, 0, 0};
            if (quad == 0)
                ga = *(const bf16x8*)&g_lds[buf][(jt * 16 + ln) * 8];
            s[jt] = __builtin_amdgcn_mfma_f32_16x16x32_bf16(
                        ga, f_frag, (f32x4){0.f, 0.f, 0.f, 0.f}, 0, 0, 0);
        }

        // ---- online softmax for column i (lanes i,i+16,i+32,i+48 cooperate)
        float lmax = -INFINITY;
#pragma unroll
        for (int jt = 0; jt < 4; ++jt)
#pragma unroll
            for (int r = 0; r < 4; ++r) lmax = fmaxf(lmax, s[jt][r]);
        lmax = fmaxf(lmax, __shfl_xor(lmax, 16));
        lmax = fmaxf(lmax, __shfl_xor(lmax, 32));
        const float new_m = fmaxf(m_i, lmax);
        const float alpha = __expf(m_i - new_m);   // 0 on first tile
        float lsum = 0.f;
        u16 pu[16];
#pragma unroll
        for (int jt = 0; jt < 4; ++jt)
#pragma unroll
            for (int r = 0; r < 4; ++r) {
                const float p = __expf(s[jt][r] - new_m);
                lsum += p;
                pu[jt * 4 + r] = f2bf(p);
            }
        lsum += __shfl_xor(lsum, 16);
        lsum += __shfl_xor(lsum, 32);
        l_i = alpha * l_i + lsum;
        m_i = new_m;

        // ---- write P (bf16) to LDS: row i = wave*16+ln, 4 j's per jt
#pragma unroll
        for (int jt = 0; jt < 4; ++jt) {
            union { u16 u[4]; uint2 v; } pk;
            pk.u[0] = pu[jt * 4 + 0]; pk.u[1] = pu[jt * 4 + 1];
            pk.u[2] = pu[jt * 4 + 2]; pk.u[3] = pu[jt * 4 + 3];
            *(uint2*)&p_lds[(wave * 16 + ln) * 72 + jt * 16 + quad * 4] = pk.v;
        }
        __syncthreads();   // #2: P visible (lgkm only; no vm outstanding)

        // ---- prefetch next tile while we do PV
        if (kt + 1 < NT) stage(kt + 1, buf ^ 1);

        // ---- PV: acc[c][i] += hv[c][j] * P[j][i]
#pragma unroll
        for (int ct = 0; ct < 4; ++ct) acc[ct] *= alpha;

        bf16x8 pb[2];
#pragma unroll
        for (int ks = 0; ks < 2; ++ks)
            pb[ks] = *(const bf16x8*)&p_lds[(wave * 16 + ln) * 72 + ks * 32 + quad * 8];

#pragma unroll
        for (int ct = 0; ct < 4; ++ct) {
            const int c = ct * 16 + ln;
#pragma unroll
            for (int ks = 0; ks < 2; ++ks) {
                const int jg = (ks * 4 + quad) ^ (ln & 7);   // undo XOR swizzle
                bf16x8 ha = *(const bf16x8*)&hv_lds[buf][c * 64 + jg * 8];
                acc[ct] = __builtin_amdgcn_mfma_f32_16x16x32_bf16(
                              ha, pb[ks], acc[ct], 0, 0, 0);
            }
        }
        buf ^= 1;
    }

    // ---- epilogue: out = gamma * o/l + x   (l_i fully reduced in every lane)
    const float gam = gamma[0];
    const float rl  = 1.f / l_i;
    const int   i   = i0 + wave * 16 + ln;
#pragma unroll
    for (int ct = 0; ct < 4; ++ct)
#pragma unroll
        for (int r = 0; r < 4; ++r) {
            const int c = ct * 16 + quad * 4 + r;
            const size_t idx = (size_t)b * CCH * NPIX + (size_t)c * NPIX + i;
            out[idx] = gam * (acc[ct][r] * rl) + x[idx];
        }
}

// ---------------------------------------------------------------------------
extern "C" void kernel_launch(void* const* d_in, const int* in_sizes, int n_in,
                              void* d_out, int out_size, void* d_ws, size_t ws_size,
                              hipStream_t stream)
{
    const float* x     = (const float*)d_in[0];
    const float* Wf    = (const float*)d_in[1];
    const float* bf    = (const float*)d_in[2];
    const float* Wg    = (const float*)d_in[3];
    const float* bg    = (const float*)d_in[4];
    const float* Wh    = (const float*)d_in[5];
    const float* bh    = (const float*)d_in[6];
    const float* gamma = (const float*)d_in[7];
    float* out = (float*)d_out;

    u16* fT = (u16*)d_ws;                       // [B][N][8]  256 KB
    u16* gT = fT + (size_t)BATCH * NPIX * 8;    // [B][N][8]  256 KB
    u16* hv = gT + (size_t)BATCH * NPIX * 8;    // [B][64][N]   2 MB

    dim3 g1(NPIX / 256, 5, BATCH);
    proj_kernel<<<g1, dim3(256), 0, stream>>>(x, Wf, bf, Wg, bg, Wh, bh, fT, gT, hv);

    dim3 g2(NPIX / TQ, BATCH);
    attn_kernel<<<g2, dim3(256), 0, stream>>>(fT, gT, hv, x, gamma, out);
}